// Round 1
// baseline (377.960 us; speedup 1.0000x reference)
//
#include <hip/hip_runtime.h>
#include <cmath>

#define C_SCALE 0.18033688011112042f   // 0.125 * log2(e)

typedef __attribute__((ext_vector_type(8))) short bf16x8;
typedef __attribute__((ext_vector_type(8))) _Float16 half8;
typedef __attribute__((ext_vector_type(4))) _Float16 half4;
typedef __attribute__((ext_vector_type(4))) float f32x4;
typedef __attribute__((ext_vector_type(4))) unsigned short us4;

__device__ inline unsigned short bf16_rne(float f) {
    unsigned u = __builtin_bit_cast(unsigned, f);
    u += 0x7fff + ((u >> 16) & 1);
    return (unsigned short)(u >> 16);
}

__device__ inline void lds_dma16(const _Float16* g, _Float16* l) {
    __builtin_amdgcn_global_load_lds(
        (__attribute__((address_space(1))) void*)(void*)g,
        (__attribute__((address_space(3))) void*)(void*)l, 16, 0, 0);
}

// ---------------------------------------------------------------------------
// Fused prep: bx<1280 -> transpose W matrices fp32->fp16 (Wt[col][k]);
// bx>=1280 -> fp32->fp16 convert of x/mem/rel.
// ---------------------------------------------------------------------------
__global__ __launch_bounds__(256) void prep_kernel(
    const float* __restrict__ x, const float* __restrict__ mem,
    const float* __restrict__ rel,
    const float* __restrict__ s0, const float* __restrict__ s1,
    const float* __restrict__ s2, const float* __restrict__ s3,
    const float* __restrict__ s4,
    _Float16* __restrict__ x16, _Float16* __restrict__ mem16,
    _Float16* __restrict__ rel16,
    _Float16* __restrict__ d0, _Float16* __restrict__ d1,
    _Float16* __restrict__ d2, _Float16* __restrict__ d3,
    _Float16* __restrict__ d4)
{
    const int bx = blockIdx.x, tid = threadIdx.x;
    if (bx < 1280) {
        __shared__ _Float16 T[64][72];
        const int z = bx >> 8, rem = bx & 255;
        const float* src = z == 0 ? s0 : z == 1 ? s1 : z == 2 ? s2 : z == 3 ? s3 : s4;
        _Float16*    dst = z == 0 ? d0 : z == 1 ? d1 : z == 2 ? d2 : z == 3 ? d3 : d4;
        const int r0 = (rem & 15) * 64, c0 = (rem >> 4) * 64;
        const int r = tid >> 4, c4 = (tid & 15) * 4;
        #pragma unroll
        for (int rr = 0; rr < 64; rr += 16) {
            float4 v = *(const float4*)(src + (size_t)(r0 + r + rr) * 1024 + c0 + c4);
            T[c4 + 0][r + rr] = (_Float16)v.x;
            T[c4 + 1][r + rr] = (_Float16)v.y;
            T[c4 + 2][r + rr] = (_Float16)v.z;
            T[c4 + 3][r + rr] = (_Float16)v.w;
        }
        __syncthreads();
        const int orow = tid >> 2, seg = (tid & 3) * 16;
        half8 h0 = *(const half8*)&T[orow][seg];
        half8 h1 = *(const half8*)&T[orow][seg + 8];
        *(half8*)(dst + (size_t)(c0 + orow) * 1024 + r0 + seg)     = h0;
        *(half8*)(dst + (size_t)(c0 + orow) * 1024 + r0 + seg + 8) = h1;
    } else {
        size_t i = ((size_t)(bx - 1280) * 256 + tid) * 8;
        if (i >= 8389632ull) return;
        const float* src; _Float16* dst; size_t off;
        if (i < 2097152ull)      { src = x;   dst = x16;   off = i; }
        else if (i < 6291456ull) { src = mem; dst = mem16; off = i - 2097152ull; }
        else                     { src = rel; dst = rel16; off = i - 6291456ull; }
        float4 a = *(const float4*)(src + off);
        float4 b = *(const float4*)(src + off + 4);
        half8 h;
        h[0]=(_Float16)a.x; h[1]=(_Float16)a.y; h[2]=(_Float16)a.z; h[3]=(_Float16)a.w;
        h[4]=(_Float16)b.x; h[5]=(_Float16)b.y; h[6]=(_Float16)b.z; h[7]=(_Float16)b.w;
        *(half8*)(dst + off) = h;
    }
}

// ---------------------------------------------------------------------------
// 128x128-tile projection GEMM (fp16, global_load_lds, XOR swizzle, BK=64).
// bx: [0,16) Q; [16,48) K; [48,80) V(transposed out); [80,97) R. grid.y=8.
// ---------------------------------------------------------------------------
__global__ __launch_bounds__(256) void proj3_kernel(
    const _Float16* __restrict__ x16, const _Float16* __restrict__ mem16,
    const _Float16* __restrict__ rel16,
    const _Float16* __restrict__ Wqt, const _Float16* __restrict__ Wkt,
    const _Float16* __restrict__ Wvt, const _Float16* __restrict__ Wrt,
    const float* __restrict__ ub, const float* __restrict__ vb,
    unsigned short* __restrict__ qu, _Float16* __restrict__ qv,
    unsigned short* __restrict__ kb, unsigned short* __restrict__ vtb,
    _Float16* __restrict__ rb)
{
    alignas(16) __shared__ _Float16 As[128 * 64];
    alignas(16) __shared__ _Float16 Bs[128 * 64];
    const int tid = threadIdx.x;
    const int lane = tid & 63, w = tid >> 6, c = lane & 15, g = lane >> 4;
    const int bx = blockIdx.x, col0 = blockIdx.y * 128;

    int mode, row0, rowmax;
    const _Float16 *Ap, *Bp;
    if (bx < 16)      { mode = 0; row0 = bx * 128;        rowmax = 2047; Ap = x16;   Bp = Wqt; }
    else if (bx < 48) { mode = 1; row0 = (bx - 16) * 128; rowmax = 4095; Ap = mem16; Bp = Wkt; }
    else if (bx < 80) { mode = 2; row0 = (bx - 48) * 128; rowmax = 4095; Ap = mem16; Bp = Wvt; }
    else              { mode = 3; row0 = (bx - 80) * 128; rowmax = 2048; Ap = rel16; Bp = Wrt; }

    const int qr = (w & 1) * 64, qc = (w >> 1) * 64;
    const int srow = lane >> 3, phys = lane & 7;
    f32x4 acc[4][4] = {};

    for (int k0 = 0; k0 < 1024; k0 += 64) {
        #pragma unroll
        for (int q = 0; q < 4; q++) {
            int row = 32 * w + 8 * q + srow;
            int log = phys ^ (row & 7);
            int ar = row0 + row; if (ar > rowmax) ar = rowmax;
            lds_dma16(Ap + (size_t)ar * 1024 + k0 + log * 8, &As[(32 * w + 8 * q) * 64]);
            lds_dma16(Bp + (size_t)(col0 + row) * 1024 + k0 + log * 8, &Bs[(32 * w + 8 * q) * 64]);
        }
        __syncthreads();
        #pragma unroll
        for (int s = 0; s < 2; s++) {
            half8 af[4], bf[4];
            #pragma unroll
            for (int i = 0; i < 4; i++) {
                int row = qr + 16 * i + c;
                af[i] = *(const half8*)&As[row * 64 + ((4 * s + g) ^ (row & 7)) * 8];
            }
            #pragma unroll
            for (int j = 0; j < 4; j++) {
                int row = qc + 16 * j + c;
                bf[j] = *(const half8*)&Bs[row * 64 + ((4 * s + g) ^ (row & 7)) * 8];
            }
            #pragma unroll
            for (int i = 0; i < 4; i++)
                #pragma unroll
                for (int j = 0; j < 4; j++)
                    acc[i][j] = __builtin_amdgcn_mfma_f32_16x16x32_f16(af[i], bf[j], acc[i][j], 0, 0, 0);
        }
        __syncthreads();
    }

    #pragma unroll
    for (int i = 0; i < 4; i++) {
        #pragma unroll
        for (int j = 0; j < 4; j++) {
            const int cg = col0 + qc + 16 * j + c;
            const int rbase = row0 + qr + 16 * i + 4 * g;
            if (mode == 0) {
                float u = ub[cg], v = vb[cg];
                #pragma unroll
                for (int rg = 0; rg < 4; rg++) {
                    size_t o = (size_t)(rbase + rg) * 1024 + cg;
                    qu[o] = bf16_rne(acc[i][j][rg] + u);
                    qv[o] = (_Float16)((acc[i][j][rg] + v) * C_SCALE);
                }
            } else if (mode == 1) {
                #pragma unroll
                for (int rg = 0; rg < 4; rg++)
                    kb[(size_t)(rbase + rg) * 1024 + cg] = bf16_rne(acc[i][j][rg]);
            } else if (mode == 2) {
                us4 pk;
                #pragma unroll
                for (int rg = 0; rg < 4; rg++) pk[rg] = bf16_rne(acc[i][j][rg]);
                int b = rbase >> 11, s = rbase & 2047;
                *(us4*)&vtb[((size_t)(b * 16 + (cg >> 6)) * 64 + (cg & 63)) * 2048 + s] = pk;
            } else {
                #pragma unroll
                for (int rg = 0; rg < 4; rg++) {
                    int r_g = rbase + rg;
                    if (r_g < 2049)
                        rb[((size_t)(cg >> 6) * 2049 + r_g) * 64 + (cg & 63)] = (_Float16)acc[i][j][rg];
                }
            }
        }
    }
}

// ---------------------------------------------------------------------------
// Flash attention, s-split x4. Barrier-free: QK^T operand-swapped so each
// thread owns P(t=16w+c, s=16j+4g+rg); Ps/BDT are wave-private LDS bands;
// K/V fragments loaded directly from global (L2-resident slices).
// Outputs normalized o (fp16) + partition row-sum l (fp32).
// ---------------------------------------------------------------------------
__global__ __launch_bounds__(256, 5) void flash_kernel(
    const unsigned short* __restrict__ qu, const _Float16* __restrict__ qv,
    const unsigned short* __restrict__ kg, const unsigned short* __restrict__ vt,
    const _Float16* __restrict__ rb, _Float16* __restrict__ po, float* __restrict__ pl)
{
    __shared__ unsigned short Ps[64][70];   // [t_local][s_local]
    __shared__ _Float16 BDT[128][70];       // [D & 127][t_local]
    const int tid = threadIdx.x;
    const int lane = tid & 63, w = tid >> 6, c = lane & 15, g = lane >> 4;
    const int id = blockIdx.x;
    const int p_pair = id & 127;
    const int t0 = (id >> 7) * 64;
    const int bn = p_pair >> 2, part = p_pair & 3;
    const int b = bn >> 4, n = bn & 15;
    const int s_start = part * 512;

    // Q fragments (used as B operand: col = t = 16w+c, k = h)
    const unsigned short* qp = qu + (size_t)(b * 1024 + t0 + 16 * w + c) * 1024 + n * 64 + g * 8;
    bf16x8 qf0 = *(const bf16x8*)qp;
    bf16x8 qf1 = *(const bf16x8*)(qp + 32);
    const _Float16* qvp = qv + (size_t)(b * 1024 + t0 + 16 * w + c) * 1024 + n * 64 + g * 8;
    half8 av0 = *(const half8*)qvp;
    half8 av1 = *(const half8*)(qvp + 32);
    int r2 = t0 + 16 * w + c + 1; if (r2 > 1023) r2 = 1023;
    const _Float16* qvp2 = qv + (size_t)(b * 1024 + r2) * 1024 + n * 64 + g * 8;
    half8 aw0 = *(const half8*)qvp2;
    half8 aw1 = *(const half8*)(qvp2 + 32);

    const _Float16* rbase = rb + (size_t)n * 2049 * 64;
    // K fragment base (A operand: row = s, k = h): kb[b][s][n*64+h]
    const unsigned short* kbase = kg + (size_t)(b * 2048 + s_start + c) * 1024 + n * 64 + g * 8;
    // V fragment base (B operand: col = h, k = s): vt[bn][h][s]
    const unsigned short* vbase = vt + ((size_t)(bn * 64 + c)) * 2048 + s_start + g * 8;

    f32x4 o[4] = {};
    float l_loc = 0.f;

    const int d0 = s_start - t0;

    auto r_ptr = [&](int Dl) {
        int mm = (Dl <= 1026) ? (Dl + 1023 > 2048 ? 2048 : Dl + 1023) : Dl - 1027;
        return rbase + (size_t)mm * 64 + g * 8;
    };
    // BD tile: A = qv(t rows), B = r(D cols); C: row = t = 16w+4g+rg, col = D = Dbase+16j+c
    auto bd_one = [&](int Dbase, int j) {
        int Dl = Dbase + 16 * j + c;
        int Dmin = Dbase + 16 * j;
        const _Float16* rp = r_ptr(Dl);
        half8 r0 = *(const half8*)rp;
        half8 r1 = *(const half8*)(rp + 32);
        f32x4 z;
        if (Dmin + 15 <= 1026) {
            f32x4 zm = {};
            zm = __builtin_amdgcn_mfma_f32_16x16x32_f16(av0, r0, zm, 0, 0, 0);
            zm = __builtin_amdgcn_mfma_f32_16x16x32_f16(av1, r1, zm, 0, 0, 0);
            z = zm;
        } else if (Dmin >= 1027) {
            f32x4 zw = {};
            zw = __builtin_amdgcn_mfma_f32_16x16x32_f16(aw0, r0, zw, 0, 0, 0);
            zw = __builtin_amdgcn_mfma_f32_16x16x32_f16(aw1, r1, zw, 0, 0, 0);
            z = zw;
        } else {
            f32x4 zm = {}, zw = {};
            zm = __builtin_amdgcn_mfma_f32_16x16x32_f16(av0, r0, zm, 0, 0, 0);
            zm = __builtin_amdgcn_mfma_f32_16x16x32_f16(av1, r1, zm, 0, 0, 0);
            zw = __builtin_amdgcn_mfma_f32_16x16x32_f16(aw0, r0, zw, 0, 0, 0);
            zw = __builtin_amdgcn_mfma_f32_16x16x32_f16(aw1, r1, zw, 0, 0, 0);
            z = (Dl >= 1027) ? zw : zm;
        }
        if (Dl == 1026) { z[0] = 0.f; z[1] = 0.f; z[2] = 0.f; z[3] = 0.f; }
        half4 hv;
        #pragma unroll
        for (int rg = 0; rg < 4; rg++) hv[rg] = (_Float16)z[rg];
        *(half4*)&BDT[Dl & 127][16 * w + 4 * g] = hv;
    };

    for (int kk = 0; kk < 8; kk++) {
        const int diff0 = d0 + kk * 64;

        // ---- extend BD circular window (wave-private cols of BDT) ----
        if (kk == 0) {
            #pragma unroll
            for (int j = 0; j < 4; j++) bd_one(d0 - 63, j);
        }
        #pragma unroll
        for (int j = 0; j < 4; j++) bd_one(diff0 + 1, j);

        // ---- logits (swapped: A=K, B=Q -> C[s][t]) + unnormalized softmax ----
        #pragma unroll
        for (int j = 0; j < 4; j++) {
            const unsigned short* kp = kbase + (size_t)(kk * 64 + 16 * j) * 1024;
            bf16x8 kf0 = *(const bf16x8*)kp;
            bf16x8 kf1 = *(const bf16x8*)(kp + 32);
            f32x4 sa = {};
            sa = __builtin_amdgcn_mfma_f32_16x16x32_bf16(kf0, qf0, sa, 0, 0, 0);
            sa = __builtin_amdgcn_mfma_f32_16x16x32_bf16(kf1, qf1, sa, 0, 0, 0);
            // thread holds: t = 16w+c (fixed), s = 16j + 4g + rg
            const int Dbj = diff0 + 16 * j + 4 * g - 16 * w - c;
            us4 pk;
            #pragma unroll
            for (int rg = 0; rg < 4; rg++) {
                float bdt = (float)BDT[(Dbj + rg) & 127][16 * w + c];
                float p = exp2f(fmaf(sa[rg], C_SCALE, bdt));
                l_loc += p;
                pk[rg] = bf16_rne(p);
            }
            *(us4*)&Ps[16 * w + c][16 * j + 4 * g] = pk;
        }

        // ---- PV: A = P[t][s] (wave-private band), B = V^T[s][h] from global ----
        bf16x8 pf0 = *(const bf16x8*)&Ps[16 * w + c][g * 8];
        bf16x8 pf1 = *(const bf16x8*)&Ps[16 * w + c][32 + g * 8];
        #pragma unroll
        for (int j = 0; j < 4; j++) {
            const unsigned short* vp = vbase + (size_t)(16 * j) * 2048 + kk * 64;
            bf16x8 vf0 = *(const bf16x8*)vp;
            bf16x8 vf1 = *(const bf16x8*)(vp + 32);
            o[j] = __builtin_amdgcn_mfma_f32_16x16x32_bf16(pf0, vf0, o[j], 0, 0, 0);
            o[j] = __builtin_amdgcn_mfma_f32_16x16x32_bf16(pf1, vf1, o[j], 0, 0, 0);
        }
    }

    // ---- epilogue: row-sum reduce across g-groups, normalize, store ----
    // l_loc holds partial sum for t = 16w+c over s in {16j+4g+rg}.
    float s2 = l_loc;
    s2 += __shfl_xor(s2, 16);
    s2 += __shfl_xor(s2, 32);
    // s2 now = full row sum for t = 16w + c (all 4 g-groups hold it)
    if (g == 0) {
        size_t rowb = ((size_t)part * 32 + bn) * 1024 + (t0 + 16 * w + c);
        pl[rowb] = s2;
    }
    #pragma unroll
    for (int rg = 0; rg < 4; rg++) {
        // o[j][rg] is at (t = 16w + 4g + rg, h = 16j + c): fetch that row's sum
        float s2r = __shfl(s2, 4 * g + rg);
        float inv = 1.f / s2r;
        int t = t0 + 16 * w + 4 * g + rg;
        size_t rowb = ((size_t)part * 32 + bn) * 1024 + t;
        #pragma unroll
        for (int j = 0; j < 4; j++)
            po[rowb * 64 + 16 * j + c] = (_Float16)(o[j][rg] * inv);
    }
}

// ---------------------------------------------------------------------------
// Combine: attn = sum_p l_p * po_p / sum_p l_p
// ---------------------------------------------------------------------------
__global__ __launch_bounds__(256) void combine_kernel(
    const _Float16* __restrict__ po, const float* __restrict__ pl,
    _Float16* __restrict__ attn)
{
    int f = blockIdx.x * 256 + threadIdx.x;
    int h = f & 63, t = (f >> 6) & 1023, bn = f >> 16;
    float os = 0.f, ls = 0.f;
    #pragma unroll
    for (int p = 0; p < 4; p++) {
        size_t rowb = ((size_t)p * 32 + bn) * 1024 + t;
        float lp = pl[rowb];
        os += lp * (float)po[rowb * 64 + h];
        ls += lp;
    }
    int b = bn >> 4, n = bn & 15;
    attn[((size_t)b * 1024 + t) * 1024 + n * 64 + h] = (_Float16)(os / ls);
}

// ---------------------------------------------------------------------------
// Output GEMM: out[bt,f] = sum_nh attn[bt,nh]*Woutt[f,nh] + b_out[f]
// ---------------------------------------------------------------------------
__global__ __launch_bounds__(256) void out2_kernel(
    const _Float16* __restrict__ A, const _Float16* __restrict__ Bt,
    const float* __restrict__ bias, float* __restrict__ out)
{
    alignas(16) __shared__ _Float16 As[4096];
    alignas(16) __shared__ _Float16 Bs[4096];
    const int tid = threadIdx.x;
    const int lane = tid & 63, w = tid >> 6, c = lane & 15, g = lane >> 4;
    const int row0 = blockIdx.x * 64, col0 = blockIdx.y * 64;
    const int srow = 16 * w + (lane >> 3);
    const int phys = lane & 7;
    f32x4 acc[4] = {};

    for (int k0 = 0; k0 < 1024; k0 += 64) {
        #pragma unroll
        for (int q = 0; q < 2; q++) {
            int row = srow + 8 * q;
            int log = phys ^ (row & 7);
            lds_dma16(A  + (size_t)(row0 + row) * 1024 + k0 + log * 8, &As[(16 * w + 8 * q) * 64]);
            lds_dma16(Bt + (size_t)(col0 + row) * 1024 + k0 + log * 8, &Bs[(16 * w + 8 * q) * 64]);
        }
        __syncthreads();
        #pragma unroll
        for (int s = 0; s < 2; s++) {
            const int pc = ((4 * s + g) ^ (c & 7)) * 8;
            half8 af = *(const half8*)&As[(16 * w + c) * 64 + pc];
            #pragma unroll
            for (int j = 0; j < 4; j++) {
                half8 bf = *(const half8*)&Bs[(16 * j + c) * 64 + pc];
                acc[j] = __builtin_amdgcn_mfma_f32_16x16x32_f16(af, bf, acc[j], 0, 0, 0);
            }
        }
        __syncthreads();
    }
    #pragma unroll
    for (int j = 0; j < 4; j++)
        #pragma unroll
        for (int rg = 0; rg < 4; rg++) {
            int r_g = row0 + 16 * w + g * 4 + rg, cg = col0 + 16 * j + c;
            out[(size_t)r_g * 1024 + cg] = acc[j][rg] + bias[cg];
        }
}

extern "C" void kernel_launch(void* const* d_in, const int* in_sizes, int n_in,
                              void* d_out, int out_size, void* d_ws, size_t ws_size,
                              hipStream_t stream)
{
    const float* x    = (const float*)d_in[0];
    const float* rel  = (const float*)d_in[1];
    const float* mem  = (const float*)d_in[2];
    const float* Wq   = (const float*)d_in[3];
    const float* Wk   = (const float*)d_in[4];
    const float* Wv   = (const float*)d_in[5];
    const float* Wr   = (const float*)d_in[6];
    const float* ub   = (const float*)d_in[7];
    const float* vb   = (const float*)d_in[8];
    const float* Wout = (const float*)d_in[9];
    const float* bout = (const float*)d_in[10];
    float* out = (float*)d_out;

    char* ws = (char*)d_ws;
    unsigned short* qu    = (unsigned short*)(ws);                   // 4 MB   bf16 [B,T,NH]
    _Float16*       qv    = (_Float16*)(ws + (4ull << 20));          // 4 MB   fp16 [B,T,NH] (*C_SCALE)
    unsigned short* kb    = (unsigned short*)(ws + (8ull << 20));    // 8 MB   bf16 [B,S,NH]
    unsigned short* vtb   = (unsigned short*)(ws + (16ull << 20));   // 8 MB   bf16 [B,N,H,S]
    _Float16*       rb    = (_Float16*)(ws + (24ull << 20));         // 4.2 MB fp16 [N,M,H]
    _Float16*       attn  = (_Float16*)(ws + (29ull << 20));         // 4 MB   fp16 [B,T,NH]
    _Float16*       po    = (_Float16*)(ws + (33ull << 20));         // 16.8MB fp16 [4,BN,T,H]
    float*          pl    = (float*)(ws + (50ull << 20));            // 0.5 MB fp32 [4,BN,T]
    _Float16*       x16   = (_Float16*)(ws + (51ull << 20));         // 4 MB
    _Float16*       mem16 = (_Float16*)(ws + (55ull << 20));         // 8 MB
    _Float16*       rel16 = (_Float16*)(ws + (63ull << 20));         // 4.2 MB
    _Float16*       Wqt   = (_Float16*)(ws + (68ull << 20));         // 2 MB each
    _Float16*       Wkt   = (_Float16*)(ws + (70ull << 20));
    _Float16*       Wvt   = (_Float16*)(ws + (72ull << 20));
    _Float16*       Wrt   = (_Float16*)(ws + (74ull << 20));
    _Float16*       Woutt = (_Float16*)(ws + (76ull << 20));

    prep_kernel<<<dim3(5377), 256, 0, stream>>>(
        x, mem, rel, Wq, Wk, Wv, Wr, Wout,
        x16, mem16, rel16, Wqt, Wkt, Wvt, Wrt, Woutt);
    proj3_kernel<<<dim3(97, 8), 256, 0, stream>>>(
        x16, mem16, rel16, Wqt, Wkt, Wvt, Wrt, ub, vb, qu, qv, kb, vtb, rb);
    flash_kernel<<<dim3(2048), 256, 0, stream>>>(qu, qv, kb, vtb, rb, po, pl);
    combine_kernel<<<dim3(8192), 256, 0, stream>>>(po, pl, attn);
    out2_kernel<<<dim3(32, 16), 256, 0, stream>>>(attn, Woutt, bout, out);
}

// Round 2
// 372.725 us; speedup vs baseline: 1.0140x; 1.0140x over previous
//
#include <hip/hip_runtime.h>
#include <cmath>

#define C_SCALE 0.18033688011112042f   // 0.125 * log2(e)

typedef __attribute__((ext_vector_type(8))) short bf16x8;
typedef __attribute__((ext_vector_type(8))) _Float16 half8;
typedef __attribute__((ext_vector_type(4))) _Float16 half4;
typedef __attribute__((ext_vector_type(4))) float f32x4;
typedef __attribute__((ext_vector_type(4))) unsigned short us4;

__device__ inline unsigned short bf16_rne(float f) {
    unsigned u = __builtin_bit_cast(unsigned, f);
    u += 0x7fff + ((u >> 16) & 1);
    return (unsigned short)(u >> 16);
}

__device__ inline void lds_dma16(const _Float16* g, _Float16* l) {
    __builtin_amdgcn_global_load_lds(
        (__attribute__((address_space(1))) void*)(void*)g,
        (__attribute__((address_space(3))) void*)(void*)l, 16, 0, 0);
}

// ---------------------------------------------------------------------------
// Fused prep: bx<1280 -> transpose W matrices fp32->fp16 (Wt[col][k]);
// bx>=1280 -> fp32->fp16 convert of x/mem/rel.
// ---------------------------------------------------------------------------
__global__ __launch_bounds__(256) void prep_kernel(
    const float* __restrict__ x, const float* __restrict__ mem,
    const float* __restrict__ rel,
    const float* __restrict__ s0, const float* __restrict__ s1,
    const float* __restrict__ s2, const float* __restrict__ s3,
    const float* __restrict__ s4,
    _Float16* __restrict__ x16, _Float16* __restrict__ mem16,
    _Float16* __restrict__ rel16,
    _Float16* __restrict__ d0, _Float16* __restrict__ d1,
    _Float16* __restrict__ d2, _Float16* __restrict__ d3,
    _Float16* __restrict__ d4)
{
    const int bx = blockIdx.x, tid = threadIdx.x;
    if (bx < 1280) {
        __shared__ _Float16 T[64][72];
        const int z = bx >> 8, rem = bx & 255;
        const float* src = z == 0 ? s0 : z == 1 ? s1 : z == 2 ? s2 : z == 3 ? s3 : s4;
        _Float16*    dst = z == 0 ? d0 : z == 1 ? d1 : z == 2 ? d2 : z == 3 ? d3 : d4;
        const int r0 = (rem & 15) * 64, c0 = (rem >> 4) * 64;
        const int r = tid >> 4, c4 = (tid & 15) * 4;
        #pragma unroll
        for (int rr = 0; rr < 64; rr += 16) {
            float4 v = *(const float4*)(src + (size_t)(r0 + r + rr) * 1024 + c0 + c4);
            T[c4 + 0][r + rr] = (_Float16)v.x;
            T[c4 + 1][r + rr] = (_Float16)v.y;
            T[c4 + 2][r + rr] = (_Float16)v.z;
            T[c4 + 3][r + rr] = (_Float16)v.w;
        }
        __syncthreads();
        const int orow = tid >> 2, seg = (tid & 3) * 16;
        half8 h0 = *(const half8*)&T[orow][seg];
        half8 h1 = *(const half8*)&T[orow][seg + 8];
        *(half8*)(dst + (size_t)(c0 + orow) * 1024 + r0 + seg)     = h0;
        *(half8*)(dst + (size_t)(c0 + orow) * 1024 + r0 + seg + 8) = h1;
    } else {
        size_t i = ((size_t)(bx - 1280) * 256 + tid) * 8;
        if (i >= 8389632ull) return;
        const float* src; _Float16* dst; size_t off;
        if (i < 2097152ull)      { src = x;   dst = x16;   off = i; }
        else if (i < 6291456ull) { src = mem; dst = mem16; off = i - 2097152ull; }
        else                     { src = rel; dst = rel16; off = i - 6291456ull; }
        float4 a = *(const float4*)(src + off);
        float4 b = *(const float4*)(src + off + 4);
        half8 h;
        h[0]=(_Float16)a.x; h[1]=(_Float16)a.y; h[2]=(_Float16)a.z; h[3]=(_Float16)a.w;
        h[4]=(_Float16)b.x; h[5]=(_Float16)b.y; h[6]=(_Float16)b.z; h[7]=(_Float16)b.w;
        *(half8*)(dst + off) = h;
    }
}

// ---------------------------------------------------------------------------
// 128x128-tile projection GEMM (fp16, global_load_lds, XOR swizzle, BK=64).
// bx: [0,16) Q; [16,48) K; [48,80) V(transposed out); [80,97) R. grid.y=8.
// ---------------------------------------------------------------------------
__global__ __launch_bounds__(256) void proj3_kernel(
    const _Float16* __restrict__ x16, const _Float16* __restrict__ mem16,
    const _Float16* __restrict__ rel16,
    const _Float16* __restrict__ Wqt, const _Float16* __restrict__ Wkt,
    const _Float16* __restrict__ Wvt, const _Float16* __restrict__ Wrt,
    const float* __restrict__ ub, const float* __restrict__ vb,
    unsigned short* __restrict__ qu, _Float16* __restrict__ qv,
    unsigned short* __restrict__ kb, unsigned short* __restrict__ vtb,
    _Float16* __restrict__ rb)
{
    alignas(16) __shared__ _Float16 As[128 * 64];
    alignas(16) __shared__ _Float16 Bs[128 * 64];
    const int tid = threadIdx.x;
    const int lane = tid & 63, w = tid >> 6, c = lane & 15, g = lane >> 4;
    const int bx = blockIdx.x, col0 = blockIdx.y * 128;

    int mode, row0, rowmax;
    const _Float16 *Ap, *Bp;
    if (bx < 16)      { mode = 0; row0 = bx * 128;        rowmax = 2047; Ap = x16;   Bp = Wqt; }
    else if (bx < 48) { mode = 1; row0 = (bx - 16) * 128; rowmax = 4095; Ap = mem16; Bp = Wkt; }
    else if (bx < 80) { mode = 2; row0 = (bx - 48) * 128; rowmax = 4095; Ap = mem16; Bp = Wvt; }
    else              { mode = 3; row0 = (bx - 80) * 128; rowmax = 2048; Ap = rel16; Bp = Wrt; }

    const int qr = (w & 1) * 64, qc = (w >> 1) * 64;
    const int srow = lane >> 3, phys = lane & 7;
    f32x4 acc[4][4] = {};

    for (int k0 = 0; k0 < 1024; k0 += 64) {
        #pragma unroll
        for (int q = 0; q < 4; q++) {
            int row = 32 * w + 8 * q + srow;
            int log = phys ^ (row & 7);
            int ar = row0 + row; if (ar > rowmax) ar = rowmax;
            lds_dma16(Ap + (size_t)ar * 1024 + k0 + log * 8, &As[(32 * w + 8 * q) * 64]);
            lds_dma16(Bp + (size_t)(col0 + row) * 1024 + k0 + log * 8, &Bs[(32 * w + 8 * q) * 64]);
        }
        __syncthreads();
        #pragma unroll
        for (int s = 0; s < 2; s++) {
            half8 af[4], bf[4];
            #pragma unroll
            for (int i = 0; i < 4; i++) {
                int row = qr + 16 * i + c;
                af[i] = *(const half8*)&As[row * 64 + ((4 * s + g) ^ (row & 7)) * 8];
            }
            #pragma unroll
            for (int j = 0; j < 4; j++) {
                int row = qc + 16 * j + c;
                bf[j] = *(const half8*)&Bs[row * 64 + ((4 * s + g) ^ (row & 7)) * 8];
            }
            #pragma unroll
            for (int i = 0; i < 4; i++)
                #pragma unroll
                for (int j = 0; j < 4; j++)
                    acc[i][j] = __builtin_amdgcn_mfma_f32_16x16x32_f16(af[i], bf[j], acc[i][j], 0, 0, 0);
        }
        __syncthreads();
    }

    #pragma unroll
    for (int i = 0; i < 4; i++) {
        #pragma unroll
        for (int j = 0; j < 4; j++) {
            const int cg = col0 + qc + 16 * j + c;
            const int rbase = row0 + qr + 16 * i + 4 * g;
            if (mode == 0) {
                float u = ub[cg], v = vb[cg];
                #pragma unroll
                for (int rg = 0; rg < 4; rg++) {
                    size_t o = (size_t)(rbase + rg) * 1024 + cg;
                    qu[o] = bf16_rne(acc[i][j][rg] + u);
                    qv[o] = (_Float16)((acc[i][j][rg] + v) * C_SCALE);
                }
            } else if (mode == 1) {
                #pragma unroll
                for (int rg = 0; rg < 4; rg++)
                    kb[(size_t)(rbase + rg) * 1024 + cg] = bf16_rne(acc[i][j][rg]);
            } else if (mode == 2) {
                us4 pk;
                #pragma unroll
                for (int rg = 0; rg < 4; rg++) pk[rg] = bf16_rne(acc[i][j][rg]);
                int b = rbase >> 11, s = rbase & 2047;
                *(us4*)&vtb[((size_t)(b * 16 + (cg >> 6)) * 64 + (cg & 63)) * 2048 + s] = pk;
            } else {
                #pragma unroll
                for (int rg = 0; rg < 4; rg++) {
                    int r_g = rbase + rg;
                    if (r_g < 2049)
                        rb[((size_t)(cg >> 6) * 2049 + r_g) * 64 + (cg & 63)] = (_Float16)acc[i][j][rg];
                }
            }
        }
    }
}

// ---------------------------------------------------------------------------
// Flash attention, s-split x4. K staged via register->LDS pipeline (one
// window ahead); V loaded direct from global in fragment layout, prefetched
// half a window ahead; r prefetched one window ahead. Swapped QK^T
// (mfma(K,Q)) so each thread owns P(t=16w+c, s=16j+4g+rg): vectorized Ps
// writes + scalar row-sum. LDS = Ks+Ps+BDT = ~36 KB -> 4 blocks/CU.
// ---------------------------------------------------------------------------
__global__ __launch_bounds__(256, 4) void flash_kernel(
    const unsigned short* __restrict__ qu, const _Float16* __restrict__ qv,
    const unsigned short* __restrict__ kg, const unsigned short* __restrict__ vt,
    const _Float16* __restrict__ rb, _Float16* __restrict__ po, float* __restrict__ pl)
{
    __shared__ unsigned short Ks[64][70];
    __shared__ unsigned short Ps[64][70];
    __shared__ _Float16 BDT[128][70];
    const int tid = threadIdx.x;
    const int lane = tid & 63, w = tid >> 6, c = lane & 15, g = lane >> 4;
    const int id = blockIdx.x;
    const int p_pair = id & 127;
    const int t0 = (id >> 7) * 64;
    const int bn = p_pair >> 2, part = p_pair & 3;
    const int b = bn >> 4, n = bn & 15;
    const int s_start = part * 512;

    // Q fragments (B operand of swapped QK^T: col = t = 16w+c, k = h)
    const unsigned short* qp = qu + (size_t)(b * 1024 + t0 + 16 * w + c) * 1024 + n * 64 + g * 8;
    bf16x8 qf0 = *(const bf16x8*)qp;
    bf16x8 qf1 = *(const bf16x8*)(qp + 32);
    const _Float16* qvp = qv + (size_t)(b * 1024 + t0 + 16 * w + c) * 1024 + n * 64 + g * 8;
    half8 av0 = *(const half8*)qvp;
    half8 av1 = *(const half8*)(qvp + 32);
    int r2 = t0 + 16 * w + c + 1; if (r2 > 1023) r2 = 1023;
    const _Float16* qvp2 = qv + (size_t)(b * 1024 + r2) * 1024 + n * 64 + g * 8;
    half8 aw0 = *(const half8*)qvp2;
    half8 aw1 = *(const half8*)(qvp2 + 32);

    const _Float16* rbase = rb + (size_t)n * 2049 * 64;
    const int sr = tid >> 2, scc = (tid & 3) * 16;
    const unsigned short* kstage = kg + (size_t)(b * 2048 + s_start + sr) * 1024 + n * 64 + scc;
    // V fragment base (B operand of PV: col = h = 16j+c, k = s): vt[bn][h][s]
    const unsigned short* vbase = vt + ((size_t)(bn * 64 + c)) * 2048 + s_start + g * 8;

    f32x4 o[4] = {};
    float l_loc = 0.f;
    const int d0 = s_start - t0;

    auto r_ptr = [&](int Dl) {
        int mm = (Dl <= 1026) ? (Dl + 1023 > 2048 ? 2048 : Dl + 1023) : Dl - 1027;
        return rbase + (size_t)mm * 64 + g * 8;
    };
    // BD tile: A = qv(t rows), B = r(D cols); C: row = t = 16w+4g+rg, col = D
    auto bd_one = [&](int Dbase, int j, half8 r0, half8 r1) {
        int Dl = Dbase + 16 * j + c;
        int Dmin = Dbase + 16 * j;
        f32x4 z;
        if (Dmin + 15 <= 1026) {
            f32x4 zm = {};
            zm = __builtin_amdgcn_mfma_f32_16x16x32_f16(av0, r0, zm, 0, 0, 0);
            zm = __builtin_amdgcn_mfma_f32_16x16x32_f16(av1, r1, zm, 0, 0, 0);
            z = zm;
        } else if (Dmin >= 1027) {
            f32x4 zw = {};
            zw = __builtin_amdgcn_mfma_f32_16x16x32_f16(aw0, r0, zw, 0, 0, 0);
            zw = __builtin_amdgcn_mfma_f32_16x16x32_f16(aw1, r1, zw, 0, 0, 0);
            z = zw;
        } else {
            f32x4 zm = {}, zw = {};
            zm = __builtin_amdgcn_mfma_f32_16x16x32_f16(av0, r0, zm, 0, 0, 0);
            zm = __builtin_amdgcn_mfma_f32_16x16x32_f16(av1, r1, zm, 0, 0, 0);
            zw = __builtin_amdgcn_mfma_f32_16x16x32_f16(aw0, r0, zw, 0, 0, 0);
            zw = __builtin_amdgcn_mfma_f32_16x16x32_f16(aw1, r1, zw, 0, 0, 0);
            z = (Dl >= 1027) ? zw : zm;
        }
        if (Dl == 1026) { z[0] = 0.f; z[1] = 0.f; z[2] = 0.f; z[3] = 0.f; }
        half4 hv;
        #pragma unroll
        for (int rg = 0; rg < 4; rg++) hv[rg] = (_Float16)z[rg];
        *(half4*)&BDT[Dl & 127][16 * w + 4 * g] = hv;
    };

    // ---- peeled window -1 BD (frees rx/rr overlap: one rr buffer only) ----
    half8 rr[8];
    #pragma unroll
    for (int j = 0; j < 4; j++) {
        const _Float16* rp = r_ptr(d0 - 63 + 16 * j + c);
        rr[2 * j] = *(const half8*)rp; rr[2 * j + 1] = *(const half8*)(rp + 32);
    }
    #pragma unroll
    for (int j = 0; j < 4; j++) bd_one(d0 - 63, j, rr[2 * j], rr[2 * j + 1]);
    #pragma unroll
    for (int j = 0; j < 4; j++) {
        const _Float16* rp = r_ptr(d0 + 1 + 16 * j + c);
        rr[2 * j] = *(const half8*)rp; rr[2 * j + 1] = *(const half8*)(rp + 32);
    }
    uint4 k0r = *(const uint4*)(kstage);
    uint4 k1r = *(const uint4*)(kstage + 8);

    for (int kk = 0; kk < 8; kk++) {
        const int diff0 = d0 + kk * 64;

        // VGPR -> LDS (K loads long since returned); BD MFMAs on resident regs
        *(uint4*)&Ks[sr][scc]     = k0r;
        *(uint4*)&Ks[sr][scc + 8] = k1r;
        #pragma unroll
        for (int j = 0; j < 4; j++) bd_one(diff0 + 1, j, rr[2 * j], rr[2 * j + 1]);

        __syncthreads();

        // ---- prefetch: next K tile + next r window; current V fragments ----
        const int kn = kk < 7 ? kk + 1 : 7;
        k0r = *(const uint4*)(kstage + (size_t)(kn * 64) * 1024);
        k1r = *(const uint4*)(kstage + (size_t)(kn * 64) * 1024 + 8);
        const int Dn = diff0 + 65;
        #pragma unroll
        for (int j = 0; j < 4; j++) {
            const _Float16* rp = r_ptr(Dn + 16 * j + c);
            rr[2 * j] = *(const half8*)rp; rr[2 * j + 1] = *(const half8*)(rp + 32);
        }
        bf16x8 vf[8];
        #pragma unroll
        for (int j = 0; j < 4; j++) {
            const unsigned short* vp = vbase + (size_t)(16 * j) * 2048 + kk * 64;
            vf[2 * j]     = *(const bf16x8*)vp;
            vf[2 * j + 1] = *(const bf16x8*)(vp + 32);
        }

        // ---- logits (swapped: A=K, B=Q -> C[s][t]) + unnormalized softmax ----
        __builtin_amdgcn_s_setprio(1);
        #pragma unroll
        for (int j = 0; j < 4; j++) {
            bf16x8 kf0 = *(const bf16x8*)&Ks[16 * j + c][g * 8];
            bf16x8 kf1 = *(const bf16x8*)&Ks[16 * j + c][32 + g * 8];
            f32x4 sa = {};
            sa = __builtin_amdgcn_mfma_f32_16x16x32_bf16(kf0, qf0, sa, 0, 0, 0);
            sa = __builtin_amdgcn_mfma_f32_16x16x32_bf16(kf1, qf1, sa, 0, 0, 0);
            // thread holds: t = 16w+c (fixed), s = 16j + 4g + rg
            const int Dbj = diff0 + 16 * j + 4 * g - 16 * w - c;
            us4 pk;
            #pragma unroll
            for (int rg = 0; rg < 4; rg++) {
                float bdt = (float)BDT[(Dbj + rg) & 127][16 * w + c];
                float p = exp2f(fmaf(sa[rg], C_SCALE, bdt));
                l_loc += p;
                pk[rg] = bf16_rne(p);
            }
            *(us4*)&Ps[16 * w + c][16 * j + 4 * g] = pk;
        }
        __builtin_amdgcn_s_setprio(0);

        // ---- PV: A = P[t][s] (wave-private band), B = V^T from registers ----
        bf16x8 pf0 = *(const bf16x8*)&Ps[16 * w + c][g * 8];
        bf16x8 pf1 = *(const bf16x8*)&Ps[16 * w + c][32 + g * 8];
        __builtin_amdgcn_s_setprio(1);
        #pragma unroll
        for (int j = 0; j < 4; j++) {
            o[j] = __builtin_amdgcn_mfma_f32_16x16x32_bf16(pf0, vf[2 * j], o[j], 0, 0, 0);
            o[j] = __builtin_amdgcn_mfma_f32_16x16x32_bf16(pf1, vf[2 * j + 1], o[j], 0, 0, 0);
        }
        __builtin_amdgcn_s_setprio(0);
        __syncthreads();
    }

    // ---- epilogue: row-sum reduce across g-groups, normalize, store ----
    float s2 = l_loc;
    s2 += __shfl_xor(s2, 16);
    s2 += __shfl_xor(s2, 32);
    if (g == 0) {
        size_t rowb = ((size_t)part * 32 + bn) * 1024 + (t0 + 16 * w + c);
        pl[rowb] = s2;
    }
    #pragma unroll
    for (int rg = 0; rg < 4; rg++) {
        float s2r = __shfl(s2, 4 * g + rg);
        float inv = 1.f / s2r;
        int t = t0 + 16 * w + 4 * g + rg;
        size_t rowb = ((size_t)part * 32 + bn) * 1024 + t;
        #pragma unroll
        for (int j = 0; j < 4; j++)
            po[rowb * 64 + 16 * j + c] = (_Float16)(o[j][rg] * inv);
    }
}

// ---------------------------------------------------------------------------
// Combine: attn = sum_p l_p * po_p / sum_p l_p
// ---------------------------------------------------------------------------
__global__ __launch_bounds__(256) void combine_kernel(
    const _Float16* __restrict__ po, const float* __restrict__ pl,
    _Float16* __restrict__ attn)
{
    int f = blockIdx.x * 256 + threadIdx.x;
    int h = f & 63, t = (f >> 6) & 1023, bn = f >> 16;
    float os = 0.f, ls = 0.f;
    #pragma unroll
    for (int p = 0; p < 4; p++) {
        size_t rowb = ((size_t)p * 32 + bn) * 1024 + t;
        float lp = pl[rowb];
        os += lp * (float)po[rowb * 64 + h];
        ls += lp;
    }
    int b = bn >> 4, n = bn & 15;
    attn[((size_t)b * 1024 + t) * 1024 + n * 64 + h] = (_Float16)(os / ls);
}

// ---------------------------------------------------------------------------
// Output GEMM: out[bt,f] = sum_nh attn[bt,nh]*Woutt[f,nh] + b_out[f]
// ---------------------------------------------------------------------------
__global__ __launch_bounds__(256) void out2_kernel(
    const _Float16* __restrict__ A, const _Float16* __restrict__ Bt,
    const float* __restrict__ bias, float* __restrict__ out)
{
    alignas(16) __shared__ _Float16 As[4096];
    alignas(16) __shared__ _Float16 Bs[4096];
    const int tid = threadIdx.x;
    const int lane = tid & 63, w = tid >> 6, c = lane & 15, g = lane >> 4;
    const int row0 = blockIdx.x * 64, col0 = blockIdx.y * 64;
    const int srow = 16 * w + (lane >> 3);
    const int phys = lane & 7;
    f32x4 acc[4] = {};

    for (int k0 = 0; k0 < 1024; k0 += 64) {
        #pragma unroll
        for (int q = 0; q < 2; q++) {
            int row = srow + 8 * q;
            int log = phys ^ (row & 7);
            lds_dma16(A  + (size_t)(row0 + row) * 1024 + k0 + log * 8, &As[(16 * w + 8 * q) * 64]);
            lds_dma16(Bt + (size_t)(col0 + row) * 1024 + k0 + log * 8, &Bs[(16 * w + 8 * q) * 64]);
        }
        __syncthreads();
        #pragma unroll
        for (int s = 0; s < 2; s++) {
            const int pc = ((4 * s + g) ^ (c & 7)) * 8;
            half8 af = *(const half8*)&As[(16 * w + c) * 64 + pc];
            #pragma unroll
            for (int j = 0; j < 4; j++) {
                half8 bf = *(const half8*)&Bs[(16 * j + c) * 64 + pc];
                acc[j] = __builtin_amdgcn_mfma_f32_16x16x32_f16(af, bf, acc[j], 0, 0, 0);
            }
        }
        __syncthreads();
    }
    #pragma unroll
    for (int j = 0; j < 4; j++)
        #pragma unroll
        for (int rg = 0; rg < 4; rg++) {
            int r_g = row0 + 16 * w + g * 4 + rg, cg = col0 + 16 * j + c;
            out[(size_t)r_g * 1024 + cg] = acc[j][rg] + bias[cg];
        }
}

extern "C" void kernel_launch(void* const* d_in, const int* in_sizes, int n_in,
                              void* d_out, int out_size, void* d_ws, size_t ws_size,
                              hipStream_t stream)
{
    const float* x    = (const float*)d_in[0];
    const float* rel  = (const float*)d_in[1];
    const float* mem  = (const float*)d_in[2];
    const float* Wq   = (const float*)d_in[3];
    const float* Wk   = (const float*)d_in[4];
    const float* Wv   = (const float*)d_in[5];
    const float* Wr   = (const float*)d_in[6];
    const float* ub   = (const float*)d_in[7];
    const float* vb   = (const float*)d_in[8];
    const float* Wout = (const float*)d_in[9];
    const float* bout = (const float*)d_in[10];
    float* out = (float*)d_out;

    char* ws = (char*)d_ws;
    unsigned short* qu    = (unsigned short*)(ws);                   // 4 MB   bf16 [B,T,NH]
    _Float16*       qv    = (_Float16*)(ws + (4ull << 20));          // 4 MB   fp16 [B,T,NH] (*C_SCALE)
    unsigned short* kb    = (unsigned short*)(ws + (8ull << 20));    // 8 MB   bf16 [B,S,NH]
    unsigned short* vtb   = (unsigned short*)(ws + (16ull << 20));   // 8 MB   bf16 [B,N,H,S]
    _Float16*       rb    = (_Float16*)(ws + (24ull << 20));         // 4.2 MB fp16 [N,M,H]
    _Float16*       attn  = (_Float16*)(ws + (29ull << 20));         // 4 MB   fp16 [B,T,NH]
    _Float16*       po    = (_Float16*)(ws + (33ull << 20));         // 16.8MB fp16 [4,BN,T,H]
    float*          pl    = (float*)(ws + (50ull << 20));            // 0.5 MB fp32 [4,BN,T]
    _Float16*       x16   = (_Float16*)(ws + (51ull << 20));         // 4 MB
    _Float16*       mem16 = (_Float16*)(ws + (55ull << 20));         // 8 MB
    _Float16*       rel16 = (_Float16*)(ws + (63ull << 20));         // 4.2 MB
    _Float16*       Wqt   = (_Float16*)(ws + (68ull << 20));         // 2 MB each
    _Float16*       Wkt   = (_Float16*)(ws + (70ull << 20));
    _Float16*       Wvt   = (_Float16*)(ws + (72ull << 20));
    _Float16*       Wrt   = (_Float16*)(ws + (74ull << 20));
    _Float16*       Woutt = (_Float16*)(ws + (76ull << 20));

    prep_kernel<<<dim3(5377), 256, 0, stream>>>(
        x, mem, rel, Wq, Wk, Wv, Wr, Wout,
        x16, mem16, rel16, Wqt, Wkt, Wvt, Wrt, Woutt);
    proj3_kernel<<<dim3(97, 8), 256, 0, stream>>>(
        x16, mem16, rel16, Wqt, Wkt, Wvt, Wrt, ub, vb, qu, qv, kb, vtb, rb);
    flash_kernel<<<dim3(2048), 256, 0, stream>>>(qu, qv, kb, vtb, rb, po, pl);
    combine_kernel<<<dim3(8192), 256, 0, stream>>>(po, pl, attn);
    out2_kernel<<<dim3(32, 16), 256, 0, stream>>>(attn, Woutt, bout, out);
}

// Round 3
// 260.301 us; speedup vs baseline: 1.4520x; 1.4319x over previous
//
#include <hip/hip_runtime.h>
#include <cmath>

#define C_SCALE 0.18033688011112042f   // 0.125 * log2(e)

typedef __attribute__((ext_vector_type(8))) short bf16x8;
typedef __attribute__((ext_vector_type(8))) _Float16 half8;
typedef __attribute__((ext_vector_type(4))) _Float16 half4;
typedef __attribute__((ext_vector_type(4))) float f32x4;
typedef __attribute__((ext_vector_type(4))) unsigned short us4;

__device__ inline unsigned short bf16_rne(float f) {
    unsigned u = __builtin_bit_cast(unsigned, f);
    u += 0x7fff + ((u >> 16) & 1);
    return (unsigned short)(u >> 16);
}

__device__ inline void lds_dma16(const _Float16* g, _Float16* l) {
    __builtin_amdgcn_global_load_lds(
        (__attribute__((address_space(1))) void*)(void*)g,
        (__attribute__((address_space(3))) void*)(void*)l, 16, 0, 0);
}

// ---------------------------------------------------------------------------
// Fused prep: bx<1280 -> transpose W matrices fp32->fp16 (Wt[col][k]);
// bx>=1280 -> fp32->fp16 convert of x/mem/rel.
// ---------------------------------------------------------------------------
__global__ __launch_bounds__(256) void prep_kernel(
    const float* __restrict__ x, const float* __restrict__ mem,
    const float* __restrict__ rel,
    const float* __restrict__ s0, const float* __restrict__ s1,
    const float* __restrict__ s2, const float* __restrict__ s3,
    const float* __restrict__ s4,
    _Float16* __restrict__ x16, _Float16* __restrict__ mem16,
    _Float16* __restrict__ rel16,
    _Float16* __restrict__ d0, _Float16* __restrict__ d1,
    _Float16* __restrict__ d2, _Float16* __restrict__ d3,
    _Float16* __restrict__ d4)
{
    const int bx = blockIdx.x, tid = threadIdx.x;
    if (bx < 1280) {
        __shared__ _Float16 T[64][72];
        const int z = bx >> 8, rem = bx & 255;
        const float* src = z == 0 ? s0 : z == 1 ? s1 : z == 2 ? s2 : z == 3 ? s3 : s4;
        _Float16*    dst = z == 0 ? d0 : z == 1 ? d1 : z == 2 ? d2 : z == 3 ? d3 : d4;
        const int r0 = (rem & 15) * 64, c0 = (rem >> 4) * 64;
        const int r = tid >> 4, c4 = (tid & 15) * 4;
        #pragma unroll
        for (int rr = 0; rr < 64; rr += 16) {
            float4 v = *(const float4*)(src + (size_t)(r0 + r + rr) * 1024 + c0 + c4);
            T[c4 + 0][r + rr] = (_Float16)v.x;
            T[c4 + 1][r + rr] = (_Float16)v.y;
            T[c4 + 2][r + rr] = (_Float16)v.z;
            T[c4 + 3][r + rr] = (_Float16)v.w;
        }
        __syncthreads();
        const int orow = tid >> 2, seg = (tid & 3) * 16;
        half8 h0 = *(const half8*)&T[orow][seg];
        half8 h1 = *(const half8*)&T[orow][seg + 8];
        *(half8*)(dst + (size_t)(c0 + orow) * 1024 + r0 + seg)     = h0;
        *(half8*)(dst + (size_t)(c0 + orow) * 1024 + r0 + seg + 8) = h1;
    } else {
        size_t i = ((size_t)(bx - 1280) * 256 + tid) * 8;
        if (i >= 8389632ull) return;
        const float* src; _Float16* dst; size_t off;
        if (i < 2097152ull)      { src = x;   dst = x16;   off = i; }
        else if (i < 6291456ull) { src = mem; dst = mem16; off = i - 2097152ull; }
        else                     { src = rel; dst = rel16; off = i - 6291456ull; }
        float4 a = *(const float4*)(src + off);
        float4 b = *(const float4*)(src + off + 4);
        half8 h;
        h[0]=(_Float16)a.x; h[1]=(_Float16)a.y; h[2]=(_Float16)a.z; h[3]=(_Float16)a.w;
        h[4]=(_Float16)b.x; h[5]=(_Float16)b.y; h[6]=(_Float16)b.z; h[7]=(_Float16)b.w;
        *(half8*)(dst + off) = h;
    }
}

// ---------------------------------------------------------------------------
// 128x128-tile projection GEMM (fp16, global_load_lds, XOR swizzle, BK=64).
// bx: [0,16) Q; [16,48) K; [48,80) V(transposed out); [80,97) R. grid.y=8.
// ---------------------------------------------------------------------------
__global__ __launch_bounds__(256) void proj3_kernel(
    const _Float16* __restrict__ x16, const _Float16* __restrict__ mem16,
    const _Float16* __restrict__ rel16,
    const _Float16* __restrict__ Wqt, const _Float16* __restrict__ Wkt,
    const _Float16* __restrict__ Wvt, const _Float16* __restrict__ Wrt,
    const float* __restrict__ ub, const float* __restrict__ vb,
    unsigned short* __restrict__ qu, _Float16* __restrict__ qv,
    unsigned short* __restrict__ kb, unsigned short* __restrict__ vtb,
    _Float16* __restrict__ rb)
{
    alignas(16) __shared__ _Float16 As[128 * 64];
    alignas(16) __shared__ _Float16 Bs[128 * 64];
    const int tid = threadIdx.x;
    const int lane = tid & 63, w = tid >> 6, c = lane & 15, g = lane >> 4;
    const int bx = blockIdx.x, col0 = blockIdx.y * 128;

    int mode, row0, rowmax;
    const _Float16 *Ap, *Bp;
    if (bx < 16)      { mode = 0; row0 = bx * 128;        rowmax = 2047; Ap = x16;   Bp = Wqt; }
    else if (bx < 48) { mode = 1; row0 = (bx - 16) * 128; rowmax = 4095; Ap = mem16; Bp = Wkt; }
    else if (bx < 80) { mode = 2; row0 = (bx - 48) * 128; rowmax = 4095; Ap = mem16; Bp = Wvt; }
    else              { mode = 3; row0 = (bx - 80) * 128; rowmax = 2048; Ap = rel16; Bp = Wrt; }

    const int qr = (w & 1) * 64, qc = (w >> 1) * 64;
    const int srow = lane >> 3, phys = lane & 7;
    f32x4 acc[4][4] = {};

    for (int k0 = 0; k0 < 1024; k0 += 64) {
        #pragma unroll
        for (int q = 0; q < 4; q++) {
            int row = 32 * w + 8 * q + srow;
            int log = phys ^ (row & 7);
            int ar = row0 + row; if (ar > rowmax) ar = rowmax;
            lds_dma16(Ap + (size_t)ar * 1024 + k0 + log * 8, &As[(32 * w + 8 * q) * 64]);
            lds_dma16(Bp + (size_t)(col0 + row) * 1024 + k0 + log * 8, &Bs[(32 * w + 8 * q) * 64]);
        }
        __syncthreads();
        #pragma unroll
        for (int s = 0; s < 2; s++) {
            half8 af[4], bf[4];
            #pragma unroll
            for (int i = 0; i < 4; i++) {
                int row = qr + 16 * i + c;
                af[i] = *(const half8*)&As[row * 64 + ((4 * s + g) ^ (row & 7)) * 8];
            }
            #pragma unroll
            for (int j = 0; j < 4; j++) {
                int row = qc + 16 * j + c;
                bf[j] = *(const half8*)&Bs[row * 64 + ((4 * s + g) ^ (row & 7)) * 8];
            }
            #pragma unroll
            for (int i = 0; i < 4; i++)
                #pragma unroll
                for (int j = 0; j < 4; j++)
                    acc[i][j] = __builtin_amdgcn_mfma_f32_16x16x32_f16(af[i], bf[j], acc[i][j], 0, 0, 0);
        }
        __syncthreads();
    }

    #pragma unroll
    for (int i = 0; i < 4; i++) {
        #pragma unroll
        for (int j = 0; j < 4; j++) {
            const int cg = col0 + qc + 16 * j + c;
            const int rbase = row0 + qr + 16 * i + 4 * g;
            if (mode == 0) {
                float u = ub[cg], v = vb[cg];
                #pragma unroll
                for (int rg = 0; rg < 4; rg++) {
                    size_t o = (size_t)(rbase + rg) * 1024 + cg;
                    qu[o] = bf16_rne(acc[i][j][rg] + u);
                    qv[o] = (_Float16)((acc[i][j][rg] + v) * C_SCALE);
                }
            } else if (mode == 1) {
                #pragma unroll
                for (int rg = 0; rg < 4; rg++)
                    kb[(size_t)(rbase + rg) * 1024 + cg] = bf16_rne(acc[i][j][rg]);
            } else if (mode == 2) {
                us4 pk;
                #pragma unroll
                for (int rg = 0; rg < 4; rg++) pk[rg] = bf16_rne(acc[i][j][rg]);
                int b = rbase >> 11, s = rbase & 2047;
                *(us4*)&vtb[((size_t)(b * 16 + (cg >> 6)) * 64 + (cg & 63)) * 2048 + s] = pk;
            } else {
                #pragma unroll
                for (int rg = 0; rg < 4; rg++) {
                    int r_g = rbase + rg;
                    if (r_g < 2049)
                        rb[((size_t)(cg >> 6) * 2049 + r_g) * 64 + (cg & 63)] = (_Float16)acc[i][j][rg];
                }
            }
        }
    }
}

// ---------------------------------------------------------------------------
// Flash attention, s-split x4. r0's proven pipeline: K AND V uint4 register
// prefetch (one window ahead) -> LDS; r prefetched one window ahead.
// Swapped QK^T (mfma(K,Q)) so each thread owns P(t=16w+c, s=16j+4g+rg):
// us4 Ps writes + scalar row-sum. Pads: 72 (16B-aligned rows) for Ks/Vs/Ps,
// 68 for BDT (8B-aligned half4). LDS 45,056 -> 3 blocks/CU. No VGPR cap
// (r2 lesson: a cap here spills ~270 MB of scratch).
// ---------------------------------------------------------------------------
__global__ __launch_bounds__(256) void flash_kernel(
    const unsigned short* __restrict__ qu, const _Float16* __restrict__ qv,
    const unsigned short* __restrict__ kg, const unsigned short* __restrict__ vt,
    const _Float16* __restrict__ rb, _Float16* __restrict__ po, float* __restrict__ pl)
{
    __shared__ unsigned short Ks[64][72];
    __shared__ unsigned short Vs[64][72];
    __shared__ unsigned short Ps[64][72];
    __shared__ _Float16 BDT[128][68];
    const int tid = threadIdx.x;
    const int lane = tid & 63, w = tid >> 6, c = lane & 15, g = lane >> 4;
    const int id = blockIdx.x;
    const int p_pair = id & 127;
    const int t0 = (id >> 7) * 64;
    const int bn = p_pair >> 2, part = p_pair & 3;
    const int b = bn >> 4, n = bn & 15;
    const int s_start = part * 512;

    // Q fragments (B operand of swapped QK^T: col = t = 16w+c, k = h)
    const unsigned short* qp = qu + (size_t)(b * 1024 + t0 + 16 * w + c) * 1024 + n * 64 + g * 8;
    bf16x8 qf0 = *(const bf16x8*)qp;
    bf16x8 qf1 = *(const bf16x8*)(qp + 32);
    const _Float16* qvp = qv + (size_t)(b * 1024 + t0 + 16 * w + c) * 1024 + n * 64 + g * 8;
    half8 av0 = *(const half8*)qvp;
    half8 av1 = *(const half8*)(qvp + 32);
    int r2 = t0 + 16 * w + c + 1; if (r2 > 1023) r2 = 1023;
    const _Float16* qvp2 = qv + (size_t)(b * 1024 + r2) * 1024 + n * 64 + g * 8;
    half8 aw0 = *(const half8*)qvp2;
    half8 aw1 = *(const half8*)(qvp2 + 32);

    const _Float16* rbase = rb + (size_t)n * 2049 * 64;
    const int sr = tid >> 2, scc = (tid & 3) * 16;
    const unsigned short* kstage = kg + (size_t)(b * 2048 + s_start + sr) * 1024 + n * 64 + scc;
    const unsigned short* vstage = vt + ((size_t)bn * 64 + sr) * 2048 + s_start + scc;

    f32x4 o[4] = {};
    float l_loc = 0.f;
    const int d0 = s_start - t0;

    auto r_ptr = [&](int Dl) {
        int mm = (Dl <= 1026) ? (Dl + 1023 > 2048 ? 2048 : Dl + 1023) : Dl - 1027;
        return rbase + (size_t)mm * 64 + g * 8;
    };
    // BD tile: A = qv(t rows), B = r(D cols); C: row = t = 16w+4g+rg, col = D
    auto bd_one = [&](int Dbase, int j, half8 r0, half8 r1) {
        int Dl = Dbase + 16 * j + c;
        int Dmin = Dbase + 16 * j;
        f32x4 z;
        if (Dmin + 15 <= 1026) {
            f32x4 zm = {};
            zm = __builtin_amdgcn_mfma_f32_16x16x32_f16(av0, r0, zm, 0, 0, 0);
            zm = __builtin_amdgcn_mfma_f32_16x16x32_f16(av1, r1, zm, 0, 0, 0);
            z = zm;
        } else if (Dmin >= 1027) {
            f32x4 zw = {};
            zw = __builtin_amdgcn_mfma_f32_16x16x32_f16(aw0, r0, zw, 0, 0, 0);
            zw = __builtin_amdgcn_mfma_f32_16x16x32_f16(aw1, r1, zw, 0, 0, 0);
            z = zw;
        } else {
            f32x4 zm = {}, zw = {};
            zm = __builtin_amdgcn_mfma_f32_16x16x32_f16(av0, r0, zm, 0, 0, 0);
            zm = __builtin_amdgcn_mfma_f32_16x16x32_f16(av1, r1, zm, 0, 0, 0);
            zw = __builtin_amdgcn_mfma_f32_16x16x32_f16(aw0, r0, zw, 0, 0, 0);
            zw = __builtin_amdgcn_mfma_f32_16x16x32_f16(aw1, r1, zw, 0, 0, 0);
            z = (Dl >= 1027) ? zw : zm;
        }
        if (Dl == 1026) { z[0] = 0.f; z[1] = 0.f; z[2] = 0.f; z[3] = 0.f; }
        half4 hv;
        #pragma unroll
        for (int rg = 0; rg < 4; rg++) hv[rg] = (_Float16)z[rg];
        *(half4*)&BDT[Dl & 127][16 * w + 4 * g] = hv;
    };

    // ---- peeled window -1 BD (only one rr buffer ever live) ----
    half8 rr[8];
    #pragma unroll
    for (int j = 0; j < 4; j++) {
        const _Float16* rp = r_ptr(d0 - 63 + 16 * j + c);
        rr[2 * j] = *(const half8*)rp; rr[2 * j + 1] = *(const half8*)(rp + 32);
    }
    #pragma unroll
    for (int j = 0; j < 4; j++) bd_one(d0 - 63, j, rr[2 * j], rr[2 * j + 1]);
    #pragma unroll
    for (int j = 0; j < 4; j++) {
        const _Float16* rp = r_ptr(d0 + 1 + 16 * j + c);
        rr[2 * j] = *(const half8*)rp; rr[2 * j + 1] = *(const half8*)(rp + 32);
    }
    uint4 k0r = *(const uint4*)(kstage);
    uint4 k1r = *(const uint4*)(kstage + 8);
    uint4 v0r = *(const uint4*)(vstage);
    uint4 v1r = *(const uint4*)(vstage + 8);

    for (int kk = 0; kk < 8; kk++) {
        const int diff0 = d0 + kk * 64;

        // VGPR -> LDS (loads long since returned); BD MFMAs on resident regs
        *(uint4*)&Ks[sr][scc]     = k0r;
        *(uint4*)&Ks[sr][scc + 8] = k1r;
        *(uint4*)&Vs[sr][scc]     = v0r;
        *(uint4*)&Vs[sr][scc + 8] = v1r;
        #pragma unroll
        for (int j = 0; j < 4; j++) bd_one(diff0 + 1, j, rr[2 * j], rr[2 * j + 1]);

        __syncthreads();

        // ---- prefetch tile kk+1 into registers (overlaps softmax/PV) ----
        const int kn = kk < 7 ? kk + 1 : 7;
        k0r = *(const uint4*)(kstage + (size_t)(kn * 64) * 1024);
        k1r = *(const uint4*)(kstage + (size_t)(kn * 64) * 1024 + 8);
        v0r = *(const uint4*)(vstage + kn * 64);
        v1r = *(const uint4*)(vstage + kn * 64 + 8);
        const int Dn = diff0 + 65;
        #pragma unroll
        for (int j = 0; j < 4; j++) {
            const _Float16* rp = r_ptr(Dn + 16 * j + c);
            rr[2 * j] = *(const half8*)rp; rr[2 * j + 1] = *(const half8*)(rp + 32);
        }

        // ---- logits (swapped: A=K, B=Q -> C[s][t]) + unnormalized softmax ----
        __builtin_amdgcn_s_setprio(1);
        #pragma unroll
        for (int j = 0; j < 4; j++) {
            bf16x8 kf0 = *(const bf16x8*)&Ks[16 * j + c][g * 8];
            bf16x8 kf1 = *(const bf16x8*)&Ks[16 * j + c][32 + g * 8];
            f32x4 sa = {};
            sa = __builtin_amdgcn_mfma_f32_16x16x32_bf16(kf0, qf0, sa, 0, 0, 0);
            sa = __builtin_amdgcn_mfma_f32_16x16x32_bf16(kf1, qf1, sa, 0, 0, 0);
            // thread holds: t = 16w+c (fixed), s = 16j + 4g + rg
            const int Dbj = diff0 + 16 * j + 4 * g - 16 * w - c;
            us4 pk;
            #pragma unroll
            for (int rg = 0; rg < 4; rg++) {
                float bdt = (float)BDT[(Dbj + rg) & 127][16 * w + c];
                float p = exp2f(fmaf(sa[rg], C_SCALE, bdt));
                l_loc += p;
                pk[rg] = bf16_rne(p);
            }
            *(us4*)&Ps[16 * w + c][16 * j + 4 * g] = pk;
        }
        __builtin_amdgcn_s_setprio(0);

        // ---- PV: A = P[t][s] (wave-private band), B = V^T[s][h] from LDS ----
        bf16x8 pf0 = *(const bf16x8*)&Ps[16 * w + c][g * 8];
        bf16x8 pf1 = *(const bf16x8*)&Ps[16 * w + c][32 + g * 8];
        __builtin_amdgcn_s_setprio(1);
        #pragma unroll
        for (int j = 0; j < 4; j++) {
            bf16x8 vf0 = *(const bf16x8*)&Vs[16 * j + c][g * 8];
            bf16x8 vf1 = *(const bf16x8*)&Vs[16 * j + c][32 + g * 8];
            o[j] = __builtin_amdgcn_mfma_f32_16x16x32_bf16(pf0, vf0, o[j], 0, 0, 0);
            o[j] = __builtin_amdgcn_mfma_f32_16x16x32_bf16(pf1, vf1, o[j], 0, 0, 0);
        }
        __builtin_amdgcn_s_setprio(0);
        __syncthreads();
    }

    // ---- epilogue: row-sum reduce across g-groups, normalize, store ----
    float s2 = l_loc;
    s2 += __shfl_xor(s2, 16);
    s2 += __shfl_xor(s2, 32);
    if (g == 0) {
        size_t rowb = ((size_t)part * 32 + bn) * 1024 + (t0 + 16 * w + c);
        pl[rowb] = s2;
    }
    #pragma unroll
    for (int rg = 0; rg < 4; rg++) {
        float s2r = __shfl(s2, 4 * g + rg);
        float inv = 1.f / s2r;
        int t = t0 + 16 * w + 4 * g + rg;
        size_t rowb = ((size_t)part * 32 + bn) * 1024 + t;
        #pragma unroll
        for (int j = 0; j < 4; j++)
            po[rowb * 64 + 16 * j + c] = (_Float16)(o[j][rg] * inv);
    }
}

// ---------------------------------------------------------------------------
// Combine: attn = sum_p l_p * po_p / sum_p l_p
// ---------------------------------------------------------------------------
__global__ __launch_bounds__(256) void combine_kernel(
    const _Float16* __restrict__ po, const float* __restrict__ pl,
    _Float16* __restrict__ attn)
{
    int f = blockIdx.x * 256 + threadIdx.x;
    int h = f & 63, t = (f >> 6) & 1023, bn = f >> 16;
    float os = 0.f, ls = 0.f;
    #pragma unroll
    for (int p = 0; p < 4; p++) {
        size_t rowb = ((size_t)p * 32 + bn) * 1024 + t;
        float lp = pl[rowb];
        os += lp * (float)po[rowb * 64 + h];
        ls += lp;
    }
    int b = bn >> 4, n = bn & 15;
    attn[((size_t)b * 1024 + t) * 1024 + n * 64 + h] = (_Float16)(os / ls);
}

// ---------------------------------------------------------------------------
// Output GEMM: out[bt,f] = sum_nh attn[bt,nh]*Woutt[f,nh] + b_out[f]
// ---------------------------------------------------------------------------
__global__ __launch_bounds__(256) void out2_kernel(
    const _Float16* __restrict__ A, const _Float16* __restrict__ Bt,
    const float* __restrict__ bias, float* __restrict__ out)
{
    alignas(16) __shared__ _Float16 As[4096];
    alignas(16) __shared__ _Float16 Bs[4096];
    const int tid = threadIdx.x;
    const int lane = tid & 63, w = tid >> 6, c = lane & 15, g = lane >> 4;
    const int row0 = blockIdx.x * 64, col0 = blockIdx.y * 64;
    const int srow = 16 * w + (lane >> 3);
    const int phys = lane & 7;
    f32x4 acc[4] = {};

    for (int k0 = 0; k0 < 1024; k0 += 64) {
        #pragma unroll
        for (int q = 0; q < 2; q++) {
            int row = srow + 8 * q;
            int log = phys ^ (row & 7);
            lds_dma16(A  + (size_t)(row0 + row) * 1024 + k0 + log * 8, &As[(16 * w + 8 * q) * 64]);
            lds_dma16(Bt + (size_t)(col0 + row) * 1024 + k0 + log * 8, &Bs[(16 * w + 8 * q) * 64]);
        }
        __syncthreads();
        #pragma unroll
        for (int s = 0; s < 2; s++) {
            const int pc = ((4 * s + g) ^ (c & 7)) * 8;
            half8 af = *(const half8*)&As[(16 * w + c) * 64 + pc];
            #pragma unroll
            for (int j = 0; j < 4; j++) {
                half8 bf = *(const half8*)&Bs[(16 * j + c) * 64 + pc];
                acc[j] = __builtin_amdgcn_mfma_f32_16x16x32_f16(af, bf, acc[j], 0, 0, 0);
            }
        }
        __syncthreads();
    }
    #pragma unroll
    for (int j = 0; j < 4; j++)
        #pragma unroll
        for (int rg = 0; rg < 4; rg++) {
            int r_g = row0 + 16 * w + g * 4 + rg, cg = col0 + 16 * j + c;
            out[(size_t)r_g * 1024 + cg] = acc[j][rg] + bias[cg];
        }
}

extern "C" void kernel_launch(void* const* d_in, const int* in_sizes, int n_in,
                              void* d_out, int out_size, void* d_ws, size_t ws_size,
                              hipStream_t stream)
{
    const float* x    = (const float*)d_in[0];
    const float* rel  = (const float*)d_in[1];
    const float* mem  = (const float*)d_in[2];
    const float* Wq   = (const float*)d_in[3];
    const float* Wk   = (const float*)d_in[4];
    const float* Wv   = (const float*)d_in[5];
    const float* Wr   = (const float*)d_in[6];
    const float* ub   = (const float*)d_in[7];
    const float* vb   = (const float*)d_in[8];
    const float* Wout = (const float*)d_in[9];
    const float* bout = (const float*)d_in[10];
    float* out = (float*)d_out;

    char* ws = (char*)d_ws;
    unsigned short* qu    = (unsigned short*)(ws);                   // 4 MB   bf16 [B,T,NH]
    _Float16*       qv    = (_Float16*)(ws + (4ull << 20));          // 4 MB   fp16 [B,T,NH] (*C_SCALE)
    unsigned short* kb    = (unsigned short*)(ws + (8ull << 20));    // 8 MB   bf16 [B,S,NH]
    unsigned short* vtb   = (unsigned short*)(ws + (16ull << 20));   // 8 MB   bf16 [B,N,H,S]
    _Float16*       rb    = (_Float16*)(ws + (24ull << 20));         // 4.2 MB fp16 [N,M,H]
    _Float16*       attn  = (_Float16*)(ws + (29ull << 20));         // 4 MB   fp16 [B,T,NH]
    _Float16*       po    = (_Float16*)(ws + (33ull << 20));         // 16.8MB fp16 [4,BN,T,H]
    float*          pl    = (float*)(ws + (50ull << 20));            // 0.5 MB fp32 [4,BN,T]
    _Float16*       x16   = (_Float16*)(ws + (51ull << 20));         // 4 MB
    _Float16*       mem16 = (_Float16*)(ws + (55ull << 20));         // 8 MB
    _Float16*       rel16 = (_Float16*)(ws + (63ull << 20));         // 4.2 MB
    _Float16*       Wqt   = (_Float16*)(ws + (68ull << 20));         // 2 MB each
    _Float16*       Wkt   = (_Float16*)(ws + (70ull << 20));
    _Float16*       Wvt   = (_Float16*)(ws + (72ull << 20));
    _Float16*       Wrt   = (_Float16*)(ws + (74ull << 20));
    _Float16*       Woutt = (_Float16*)(ws + (76ull << 20));

    prep_kernel<<<dim3(5377), 256, 0, stream>>>(
        x, mem, rel, Wq, Wk, Wv, Wr, Wout,
        x16, mem16, rel16, Wqt, Wkt, Wvt, Wrt, Woutt);
    proj3_kernel<<<dim3(97, 8), 256, 0, stream>>>(
        x16, mem16, rel16, Wqt, Wkt, Wvt, Wrt, ub, vb, qu, qv, kb, vtb, rb);
    flash_kernel<<<dim3(2048), 256, 0, stream>>>(qu, qv, kb, vtb, rb, po, pl);
    combine_kernel<<<dim3(8192), 256, 0, stream>>>(po, pl, attn);
    out2_kernel<<<dim3(32, 16), 256, 0, stream>>>(attn, Woutt, bout, out);
}